// Round 1
// baseline (126.454 us; speedup 1.0000x reference)
//
#include <hip/hip_runtime.h>
#include <hip/hip_fp16.h>

// Problem constants (fixed by the reference setup)
constexpr int N = 4096;
constexpr int D = 512;
constexpr int NT = 32;                   // 4096 / 128 tile-rows
constexpr int NBLK = NT * (NT + 1) / 2;  // 528 upper-triangle tiles
constexpr int NWM = NBLK * 8;            // 4224 per-wave 64x32 region maxes
constexpr float SENT = -1e30f;           // sentinel (invalid sites / empty slots)
constexpr unsigned TCV = 8386560u;       // N*(N-1)/2 valid strict-upper pairs

typedef _Float16 f16x8 __attribute__((ext_vector_type(8)));
typedef float f32x4 __attribute__((ext_vector_type(4)));

// async 16B/lane global->LDS (wave-uniform LDS base + lane*16)
__device__ __forceinline__ void load_lds16(const _Float16* g, _Float16* l) {
  __builtin_amdgcn_global_load_lds(
      (const __attribute__((address_space(1))) void*)g,
      (__attribute__((address_space(3))) void*)l, 16, 0, 0);
}

// Exact wave top-10 by repeated selection over per-lane register candidates.
// out[r] ends up wave-uniform. Duplicates preserved (leader pops ONE copy).
// NOTE: mutates vals[] on leader lanes.
template <int M>
__device__ __forceinline__ void wave_sel10(float (&vals)[M], float (&out)[10]) {
  int lane = threadIdx.x & 63;
  float lm = vals[0];
#pragma unroll
  for (int k = 1; k < M; k++) lm = fmaxf(lm, vals[k]);
#pragma unroll
  for (int r = 0; r < 10; r++) {
    float wmx = lm;
#pragma unroll
    for (int ofs = 1; ofs < 64; ofs <<= 1)
      wmx = fmaxf(wmx, __shfl_xor(wmx, ofs));
    out[r] = wmx;
    unsigned long long b = __ballot(lm == wmx);
    int leader = __ffsll(b) - 1;
    if (lane == leader) {
      bool found = false;
#pragma unroll
      for (int k = 0; k < M; k++) {
        bool hit = !found && (vals[k] == wmx);
        vals[k] = hit ? SENT : vals[k];
        found = found || hit;
      }
      lm = vals[0];
#pragma unroll
      for (int k = 1; k < M; k++) lm = fmaxf(lm, vals[k]);
    }
  }
}

// ws layout (as float indices into slots):
//   [0, 528)        f32 blk_sumv
//   [528, 1056)     f32 blk_sump
//   [1056, 1584)    u32 cntpack  (cntp | zeros<<16, per-block totals < 65536)
//   [1584, 5808)    f32 wmax[528*8]   per-wave 64x32 region maxima
//   byte 32768:     f16 Xh[N*D]
constexpr int XH_OFF = 32768;

// ---------------- K0: fp32 -> f16 convert ----------------
__global__ void prep_kernel(const float4* __restrict__ X4,
                            ushort4* __restrict__ Xh4) {
  int gid = blockIdx.x * 256 + threadIdx.x;  // grid exactly N*D/4 threads
  float4 v = X4[gid];
  ushort4 o;
  o.x = __half_as_ushort(__float2half_rn(v.x));
  o.y = __half_as_ushort(__float2half_rn(v.y));
  o.z = __half_as_ushort(__float2half_rn(v.z));
  o.w = __half_as_ushort(__float2half_rn(v.w));
  Xh4[gid] = o;
}

// ---------------- K1: 128x128-tile X*X^T, double-buffered, stats+max only ----
// 528 blocks x 512 threads (8 waves, 2M x 4N wave grid, 64x32 per wave).
// LDS 64 KB dbuf -> 2 blocks/CU (16 waves). One barrier per K-step: stage
// k0+1 into buf^1 right after the barrier; its vmcnt drains at the NEXT
// barrier, hiding L2 latency under this step's ds_read+MFMA.
// XOR swizzle identical to the verified 64-tile version: LDS pos p of row r
// holds global 16B chunk p^(r&7); read back at pos (c)^(lrow&7) (all row
// bases are multiples of 16, so row&7 == lrow&7).
__global__ __launch_bounds__(512, 4) void gemm_stats_kernel(
    const _Float16* __restrict__ Xh, const int* __restrict__ tgt,
    float* __restrict__ slots) {
  __shared__ _Float16 As[2][128 * 64];  // 2 x 16 KB
  __shared__ _Float16 Bs[2][128 * 64];  // 2 x 16 KB
  __shared__ int tA[128], tB[128];
  __shared__ float redf[2][8];
  __shared__ unsigned redu[8];

  int tid = threadIdx.x;

  // decode upper-triangle tile (br <= bc)
  int id = blockIdx.x, br = 0;
  while (id >= (NT - br)) { id -= (NT - br); br++; }
  int bc = br + id;

  if (tid < 128) tA[tid] = tgt[br * 128 + tid];
  else if (tid < 256) tB[tid - 128] = tgt[bc * 128 + (tid - 128)];

  int lane = tid & 63, wave = tid >> 6;
  int wm2 = (wave >> 2) << 6;  // 0 or 64: wave row-half
  int wn2 = (wave & 3) << 5;   // 0,32,64,96: wave col-quarter
  int lrow = lane & 15;
  int q4 = lane >> 4;
  int x7 = lrow & 7;
  int quad4 = q4 * 4;

  // staging: issue i (0..1) covers chunks C = i*512 + tid (1024 16B chunks
  // per matrix); row = C>>3, pos p = C&7 holds global chunk p^(row&7).
  int srow[2], scol[2], sdst[2];
#pragma unroll
  for (int i = 0; i < 2; i++) {
    int C = i * 512 + tid;
    int row = C >> 3, p = C & 7;
    srow[i] = row;
    scol[i] = (p ^ (row & 7)) * 8;
    sdst[i] = (i * 8 + wave) * 512;  // wave-uniform elem base (+lane*8 by HW)
  }
  const _Float16* Arow = Xh + (size_t)(br * 128) * D;
  const _Float16* Brow = Xh + (size_t)(bc * 128) * D;

  // prologue: stage k0=0 into buffer 0
#pragma unroll
  for (int i = 0; i < 2; i++) {
    load_lds16(Arow + srow[i] * D + scol[i], &As[0][sdst[i]]);
    load_lds16(Brow + srow[i] * D + scol[i], &Bs[0][sdst[i]]);
  }

  f32x4 acc[4][2] = {};
#pragma unroll
  for (int t = 0; t < 8; t++) {
    int cur = t & 1;
    // barrier drains vmcnt: buf[cur] deposits visible; all waves done
    // reading buf[cur^1] (their lgkmcnt drained before arriving)
    __syncthreads();
    if (t < 7) {
      int k0 = (t + 1) * 64;
#pragma unroll
      for (int i = 0; i < 2; i++) {
        load_lds16(Arow + srow[i] * D + k0 + scol[i], &As[cur ^ 1][sdst[i]]);
        load_lds16(Brow + srow[i] * D + k0 + scol[i], &Bs[cur ^ 1][sdst[i]]);
      }
    }
#pragma unroll
    for (int ks = 0; ks < 64; ks += 32) {
      int c0 = ks >> 3;
      f16x8 af[4], bf[2];
#pragma unroll
      for (int mi = 0; mi < 4; mi++)
        af[mi] = *(const f16x8*)&As[cur][(wm2 + mi * 16 + lrow) * 64 +
                                         ((c0 + q4) ^ x7) * 8];
#pragma unroll
      for (int ni = 0; ni < 2; ni++)
        bf[ni] = *(const f16x8*)&Bs[cur][(wn2 + ni * 16 + lrow) * 64 +
                                         ((c0 + q4) ^ x7) * 8];
#pragma unroll
      for (int mi = 0; mi < 4; mi++)
#pragma unroll
        for (int ni = 0; ni < 2; ni++)
          acc[mi][ni] = __builtin_amdgcn_mfma_f32_16x16x32_f16(
              af[mi], bf[ni], acc[mi][ni], 0, 0, 0);
    }
  }

  // ---- epilogue: stats + per-wave region max ONLY (no top-10 here) ----
  int tj[2];
#pragma unroll
  for (int ni = 0; ni < 2; ni++) tj[ni] = tB[wn2 + ni * 16 + lrow];

  float lsv = 0.f, lsp = 0.f, lmax = SENT;
  unsigned cz = 0;  // cntp | zeros<<16 (block totals <= 16384 each)
  int ib = br * 128 + wm2 + quad4;
  int jb = bc * 128 + wn2 + lrow;
#pragma unroll
  for (int mi = 0; mi < 4; mi++) {
#pragma unroll
    for (int r = 0; r < 4; r++) {
      int trow = tA[wm2 + mi * 16 + quad4 + r];
      int i = ib + mi * 16 + r;
#pragma unroll
      for (int ni = 0; ni < 2; ni++) {
        float s = acc[mi][ni][r];
        int j = jb + ni * 16;
        bool valid = j > i;  // strict upper triangle; doubled at the end
        bool pos = valid && (trow == tj[ni]);
        float loss = fmaxf(0.5f + (pos ? -s : s), 0.0f);
        if (valid) { lsv += s; if (loss == 0.0f) cz += 0x10000u; }
        if (pos) { lsp += s; cz += 1u; }
        lmax = fmaxf(lmax, valid ? loss : SENT);
      }
    }
  }
#pragma unroll
  for (int o = 32; o > 0; o >>= 1) {
    lsv += __shfl_down(lsv, o);
    lsp += __shfl_down(lsp, o);
    cz += __shfl_down(cz, o);
    lmax = fmaxf(lmax, __shfl_down(lmax, o));
  }
  if (lane == 0) {
    redf[0][wave] = lsv; redf[1][wave] = lsp; redu[wave] = cz;
    slots[3 * NBLK + blockIdx.x * 8 + wave] = lmax;  // region max to global
  }
  __syncthreads();
  if (tid == 0) {
    float a = 0.f, b = 0.f;
    unsigned c = 0;
#pragma unroll
    for (int w = 0; w < 8; w++) { a += redf[0][w]; b += redf[1][w]; c += redu[w]; }
    slots[blockIdx.x] = a;
    slots[NBLK + blockIdx.x] = b;
    ((unsigned*)slots)[2 * NBLK + blockIdx.x] = c;
  }
}

// ---------------- K2: single-block finalize with candidate recompute --------
// T = 10th-largest region max  =>  g10 >= T and every global-top-10 value
// lives in a region with max >= T (~10 regions). Recompute those regions
// BIT-IDENTICALLY (same f16 inputs, same MFMA K-order) and collect all
// values >= T; top-10 of the collected set is the exact global top-10.
__device__ __forceinline__ void load_frags(const _Float16* __restrict__ Xh,
                                           int r0, int c0, int kk, int lrow,
                                           int q4, f16x8 (&af)[4],
                                           f16x8 (&bf)[2]) {
#pragma unroll
  for (int mi = 0; mi < 4; mi++)
    af[mi] = *(const f16x8*)&Xh[(size_t)(r0 + mi * 16 + lrow) * D + kk + q4 * 8];
#pragma unroll
  for (int ni = 0; ni < 2; ni++)
    bf[ni] = *(const f16x8*)&Xh[(size_t)(c0 + ni * 16 + lrow) * D + kk + q4 * 8];
}

__device__ __forceinline__ void mfma8(f32x4 (&a4)[4][2], f16x8 (&af)[4],
                                      f16x8 (&bf)[2]) {
#pragma unroll
  for (int mi = 0; mi < 4; mi++)
#pragma unroll
    for (int ni = 0; ni < 2; ni++)
      a4[mi][ni] = __builtin_amdgcn_mfma_f32_16x16x32_f16(af[mi], bf[ni],
                                                          a4[mi][ni], 0, 0, 0);
}

__global__ __launch_bounds__(512) void finalize_kernel(
    const _Float16* __restrict__ Xh, const int* __restrict__ tgt,
    const float* __restrict__ slots, float* __restrict__ out) {
  const float* sumv = slots;
  const float* sump = slots + NBLK;
  const unsigned* cnts = (const unsigned*)(slots + 2 * NBLK);
  const float* wmax = slots + 3 * NBLK;

  __shared__ float svals[2048];
  __shared__ int scand[1024];
  __shared__ float wml[80];
  __shared__ float redf[2][8];
  __shared__ unsigned redu2[2][8];
  __shared__ float sres[2];
  __shared__ unsigned scnt2[2];
  __shared__ unsigned snc, snv;
  __shared__ float sT;

  int tid = threadIdx.x, lane = tid & 63, wave = tid >> 6;
  if (tid == 0) { snc = 0u; snv = 0u; }

  // phase 1: stats partials
  float sv = 0.f, sp = 0.f;
  unsigned cp = 0, zz = 0;
#pragma unroll
  for (int k = 0; k < 2; k++) {
    int r = tid + k * 512;
    if (r < NBLK) {
      sv += sumv[r]; sp += sump[r];
      unsigned c = cnts[r];
      cp += c & 0xffffu; zz += c >> 16;
    }
  }
  // phase 2: load region maxes (keep copies: sel10 mutates)
  float mv[9], keep[9];
#pragma unroll
  for (int k = 0; k < 9; k++) {
    int g = tid + k * 512;
    mv[k] = (g < NWM) ? wmax[g] : SENT;
    keep[k] = mv[k];
  }
#pragma unroll
  for (int o = 32; o > 0; o >>= 1) {
    sv += __shfl_down(sv, o); sp += __shfl_down(sp, o);
    cp += __shfl_down(cp, o); zz += __shfl_down(zz, o);
  }
  if (lane == 0) {
    redf[0][wave] = sv; redf[1][wave] = sp;
    redu2[0][wave] = cp; redu2[1][wave] = zz;
  }
  float wl[10];
  wave_sel10<9>(mv, wl);
  if (lane == 0) {
#pragma unroll
    for (int r = 0; r < 10; r++) wml[wave * 10 + r] = wl[r];
  }
  __syncthreads();
  if (tid == 0) {
    float a = 0.f, b = 0.f;
    unsigned c = 0, z = 0;
#pragma unroll
    for (int w = 0; w < 8; w++) {
      a += redf[0][w]; b += redf[1][w];
      c += redu2[0][w]; z += redu2[1][w];
    }
    sres[0] = a; sres[1] = b; scnt2[0] = c; scnt2[1] = z;
  }
  if (wave == 0) {
    float m2[2];
    m2[0] = wml[lane];  // lane < 64 < 80: always a real slot
    m2[1] = (lane + 64 < 80) ? wml[lane + 64] : SENT;
    float t10[10];
    wave_sel10<2>(m2, t10);
    if (lane == 0) sT = t10[9];
  }
  __syncthreads();
  float T = sT;

  // phase 3: candidate regions (max >= T)
#pragma unroll
  for (int k = 0; k < 9; k++) {
    int g = tid + k * 512;
    if (g < NWM && keep[k] >= T) {
      unsigned p = atomicAdd(&snc, 1u);
      if (p < 1024u) scand[p] = g;
    }
  }
  __syncthreads();

  // phase 4: recompute candidate 64x32 regions, collect values >= T
  int nu = (int)snc;
  if (nu > 1024) nu = 1024;
  int lrow = lane & 15, q4 = lane >> 4, quad4 = q4 * 4;
  for (int u = wave; u < nu; u += 8) {
    int g = scand[u];
    int cb = g >> 3, wr = g & 7;
    int idd = cb, br = 0;
    while (idd >= (NT - br)) { idd -= (NT - br); br++; }
    int bc = br + idd;
    int r0 = br * 128 + ((wr >> 2) << 6);
    int c0 = bc * 128 + ((wr & 3) << 5);

    f32x4 a4[4][2] = {};
    f16x8 af0[4], bf0[2], af1[4], bf1[2];
    load_frags(Xh, r0, c0, 0, lrow, q4, af0, bf0);
#pragma unroll
    for (int kk = 0; kk < D; kk += 64) {  // K-order 0,32,64,... == K1's chain
      load_frags(Xh, r0, c0, kk + 32, lrow, q4, af1, bf1);
      mfma8(a4, af0, bf0);
      if (kk + 64 < D) load_frags(Xh, r0, c0, kk + 64, lrow, q4, af0, bf0);
      mfma8(a4, af1, bf1);
    }
    int tj[2];
#pragma unroll
    for (int ni = 0; ni < 2; ni++) tj[ni] = tgt[c0 + ni * 16 + lrow];
#pragma unroll
    for (int mi = 0; mi < 4; mi++) {
#pragma unroll
      for (int r = 0; r < 4; r++) {
        int i = r0 + mi * 16 + quad4 + r;
        int trow = tgt[i];
#pragma unroll
        for (int ni = 0; ni < 2; ni++) {
          int j = c0 + ni * 16 + lrow;
          float s = a4[mi][ni][r];
          bool valid = j > i;
          bool pos = valid && (trow == tj[ni]);
          float loss = fmaxf(0.5f + (pos ? -s : s), 0.0f);
          if (valid && loss >= T) {
            unsigned p = atomicAdd(&snv, 1u);
            if (p < 2048u) svals[p] = loss;
          }
        }
      }
    }
  }
  __syncthreads();

  // phase 5: exact top-10 over collected values, final outputs
  int nv = (int)snv;
  if (nv > 2048) nv = 2048;
  float v4[4];
#pragma unroll
  for (int k = 0; k < 4; k++) {
    int g = tid + k * 512;
    v4[k] = (g < nv) ? svals[g] : SENT;
  }
  float wl2[10];
  wave_sel10<4>(v4, wl2);
  if (lane == 0) {
#pragma unroll
    for (int r = 0; r < 10; r++) wml[wave * 10 + r] = wl2[r];
  }
  __syncthreads();
  if (wave == 0) {
    float m2[2];
    m2[0] = wml[lane];
    m2[1] = (lane + 64 < 80) ? wml[lane + 64] : SENT;
    float f10[10];
    wave_sel10<2>(m2, f10);
    if (lane == 0) {
      float topsum = 0.f;
#pragma unroll
      for (int r = 0; r < 10; r++) topsum += f10[r];
      // full-matrix multiset = upper-triangle doubled: top-20 mean == top-10
      // mean; counts double in numerator and denominator (cancel in means)
      out[0] = topsum * 0.1f;
      out[1] = (float)(2u * scnt2[1]);
      out[2] = sres[1] / (float)scnt2[0];
      out[3] = (sres[0] - sres[1]) / (float)(TCV - scnt2[0]);
    }
  }
}

extern "C" void kernel_launch(void* const* d_in, const int* in_sizes, int n_in,
                              void* d_out, int out_size, void* d_ws,
                              size_t ws_size, hipStream_t stream) {
  const float* X = (const float*)d_in[0];
  const int* tgt = (const int*)d_in[1];
  float* out = (float*)d_out;
  char* ws = (char*)d_ws;

  float* slots = (float*)ws;
  _Float16* Xh = (_Float16*)(ws + XH_OFF);

  prep_kernel<<<(N * D / 4) / 256, 256, 0, stream>>>((const float4*)X,
                                                     (ushort4*)Xh);
  gemm_stats_kernel<<<NBLK, 512, 0, stream>>>(Xh, tgt, slots);
  finalize_kernel<<<1, 512, 0, stream>>>(Xh, tgt, slots, out);
}